// Round 13
// baseline (357.323 us; speedup 1.0000x reference)
//
#include <hip/hip_runtime.h>
#include <math.h>

#define TPB 256
#define TPB_PRE 512
#define SCAN_B 1024

__device__ __forceinline__ void quat_to_R(float w, float x, float y, float z, float* R) {
    R[0] = 1.f - 2.f*(y*y + z*z);
    R[1] = 2.f*(x*y - w*z);
    R[2] = 2.f*(x*z + w*y);
    R[3] = 2.f*(x*y + w*z);
    R[4] = 1.f - 2.f*(x*x + z*z);
    R[5] = 2.f*(y*z - w*x);
    R[6] = 2.f*(x*z - w*y);
    R[7] = 2.f*(y*z + w*x);
    R[8] = 1.f - 2.f*(x*x + y*y);
}

// 32-lane (half-wave) reductions: xor offsets < 32 stay within each half.
__device__ __forceinline__ float hsum32(float v) {
    #pragma unroll
    for (int o = 16; o > 0; o >>= 1) v += __shfl_xor(v, o);
    return v;
}
__device__ __forceinline__ float hmax32(float v) {
    #pragma unroll
    for (int o = 16; o > 0; o >>= 1) v = fmaxf(v, __shfl_xor(v, o));
    return v;
}

// ---------------- K0: per-node init ----------------
// qt layout per node (32 B): [w,x,y,z][t0,t1,t2,0]
// RT layout per node: [r00,r01,r02,t0][r10,r11,r12,t1][r20,r21,r22,t2]
__global__ __launch_bounds__(TPB) void k_init(
    const float* __restrict__ quats, const float* __restrict__ trans,
    float* __restrict__ qt, float* __restrict__ RT, int* __restrict__ deg, int N)
{
    int n = blockIdx.x * TPB + threadIdx.x;
    if (n >= N) return;
    float4 q = ((const float4*)quats)[n];
    float inv = rsqrtf(q.x*q.x + q.y*q.y + q.z*q.z + q.w*q.w);
    float w = q.x*inv, x = q.y*inv, y = q.z*inv, z = q.w*inv;
    float t0 = trans[(size_t)n*3+0], t1 = trans[(size_t)n*3+1], t2 = trans[(size_t)n*3+2];
    float4* qtp = (float4*)(qt + (size_t)n*8);
    qtp[0] = make_float4(w, x, y, z);
    qtp[1] = make_float4(t0, t1, t2, 0.f);
    float R[9];
    quat_to_R(w, x, y, z, R);
    float4* rt = (float4*)(RT + (size_t)n*12);
    rt[0] = make_float4(R[0], R[1], R[2], t0);
    rt[1] = make_float4(R[3], R[4], R[5], t1);
    rt[2] = make_float4(R[6], R[7], R[8], t2);
    deg[n] = 0;
}

// ---------------- K1: histogram of src + arrival rank ----------------
__global__ __launch_bounds__(TPB) void k_hist(
    const int* __restrict__ ei, int* __restrict__ deg, int* __restrict__ rank, int E)
{
    int e = blockIdx.x * TPB + threadIdx.x;
    if (e >= E) return;
    rank[e] = atomicAdd(deg + ei[(size_t)E + e], 1);
}

// ---------------- scan: deg -> row (exclusive) ----------------
__global__ __launch_bounds__(SCAN_B) void k_scan1(
    const int* __restrict__ deg, int* __restrict__ row, int* __restrict__ bsum, int N)
{
    __shared__ int sh[SCAN_B];
    int i = blockIdx.x * SCAN_B + threadIdx.x;
    int v = (i < N) ? deg[i] : 0;
    sh[threadIdx.x] = v;
    __syncthreads();
    #pragma unroll
    for (int o = 1; o < SCAN_B; o <<= 1) {
        int t = (threadIdx.x >= o) ? sh[threadIdx.x - o] : 0;
        __syncthreads();
        sh[threadIdx.x] += t;
        __syncthreads();
    }
    if (i < N) row[i] = sh[threadIdx.x] - v;
    if (threadIdx.x == SCAN_B - 1) bsum[blockIdx.x] = sh[SCAN_B - 1];
}

__global__ __launch_bounds__(SCAN_B) void k_scan2(int* __restrict__ bsum, int nb)
{
    __shared__ int sh[SCAN_B];
    int v = (threadIdx.x < nb) ? bsum[threadIdx.x] : 0;
    sh[threadIdx.x] = v;
    __syncthreads();
    #pragma unroll
    for (int o = 1; o < SCAN_B; o <<= 1) {
        int t = (threadIdx.x >= o) ? sh[threadIdx.x - o] : 0;
        __syncthreads();
        sh[threadIdx.x] += t;
        __syncthreads();
    }
    if (threadIdx.x < nb) bsum[threadIdx.x] = sh[threadIdx.x] - v;
}

__global__ __launch_bounds__(TPB) void k_scan3(
    int* __restrict__ row, const int* __restrict__ bsum, int N, int E)
{
    int i = blockIdx.x * TPB + threadIdx.x;
    if (i >= N) return;
    row[i] = row[i] + bsum[i >> 10];
    if (i == 0) row[N] = E;
}

// ---------------- K2: per-edge precompute, LDS-staged two-phase --------------
// Block handles TPB_PRE edges. No atomics: pos = row[src] + rank[e].
// Gathers for the tail (ei, qt[dst], qt[src], row, rank) are issued BEFORE the
// streaming phase so their latency hides under the 16 float4 ef loads.
// Phase 1 (stream): r=0..3, 4 thr/edge quarter-rows -> LDS accS[TPB_PRE][7].
// Phase 2 (tail): 1 thread = 1 edge, all 64 lanes active.
// Payload (32 B/edge, CSR position):
//   pay[2*pos+0] = [px, py, pz, bits(dst | signbit(pw))]
//   pay[2*pos+1] = [pt0, pt1, pt2, logit]
__global__ __launch_bounds__(TPB_PRE) void k_edge_pre(
    const float* __restrict__ ef, const int* __restrict__ ei,
    const float* __restrict__ qt,
    const float* __restrict__ Wu, const float* __restrict__ bu,
    const float* __restrict__ Wl, const float* __restrict__ bl,
    const int* __restrict__ row, const int* __restrict__ rank,
    float4* __restrict__ pay, int E)
{
    __shared__ __align__(16) float Ws[7][64];
    __shared__ float accS[TPB_PRE][7];
    for (int i = threadIdx.x; i < 7*64; i += TPB_PRE) {
        int j = i >> 6, k = i & 63;
        Ws[j][k] = (j < 6) ? Wu[k*6 + j] : Wl[k];
    }
    __syncthreads();

    int tid = threadIdx.x;
    int sub = tid & 3, eL = tid >> 2;
    int blockStart = blockIdx.x * TPB_PRE;

    // ---- hoisted tail gathers (latency hides under the stream phase) ----
    int eT = blockStart + tid;
    int pos = 0;
    float4 qd = make_float4(1.f,0.f,0.f,0.f), qs = qd;
    float4 td4 = make_float4(0.f,0.f,0.f,0.f), ts4 = td4;
    unsigned dstbits = 0;
    if (eT < E) {
        int dst = ei[eT];
        int src = ei[(size_t)E + eT];
        dstbits = (unsigned)dst;
        pos = row[src] + rank[eT];
        const float4* pd = (const float4*)(qt + (size_t)dst*8);
        const float4* ps = (const float4*)(qt + (size_t)src*8);
        qd  = pd[0]; td4 = pd[1];
        qs  = ps[0]; ts4 = ps[1];
    }

    // ---- phase 1: stream ef ----
    #pragma unroll
    for (int r = 0; r < 4; ++r) {
        int el = r * (TPB_PRE/4) + eL;
        int e = blockStart + el;
        float acc[7] = {0.f,0.f,0.f,0.f,0.f,0.f,0.f};
        if (e < E) {
            const float4* ef4 = (const float4*)(ef + (size_t)e * 64) + sub * 4;
            #pragma unroll
            for (int k = 0; k < 4; ++k) {
                float4 v = ef4[k];
                #pragma unroll
                for (int j = 0; j < 7; ++j) {
                    float4 w = ((const float4*)Ws[j])[sub*4 + k];
                    acc[j] = fmaf(v.x, w.x, fmaf(v.y, w.y, fmaf(v.z, w.z, fmaf(v.w, w.w, acc[j]))));
                }
            }
        }
        #pragma unroll
        for (int j = 0; j < 7; ++j) {
            acc[j] += __shfl_xor(acc[j], 1);
            acc[j] += __shfl_xor(acc[j], 2);
        }
        if (sub == 0) {
            #pragma unroll
            for (int j = 0; j < 7; ++j) accS[el][j] = acc[j];
        }
    }
    __syncthreads();

    // ---- phase 2: tail, 1 thread = 1 edge ----
    if (eT >= E) return;
    float acc[7];
    #pragma unroll
    for (int j = 0; j < 7; ++j) acc[j] = accS[tid][j];
    #pragma unroll
    for (int j = 0; j < 6; ++j) acc[j] += bu[j];
    acc[6] += bl[0];

    // q_rel = conj(qd) * qs
    float aw = qd.x, ax = -qd.y, ay = -qd.z, az = -qd.w;
    float bw = qs.x, bx = qs.y, by = qs.z, bz = qs.w;
    float rw = aw*bw - ax*bx - ay*by - az*bz;
    float rx = aw*bx + ax*bw + ay*bz - az*by;
    float ry = aw*by - ax*bz + ay*bw + az*bx;
    float rz = aw*bz + ax*by - ay*bx + az*bw;
    // pair_q = q_rel + q_rel * (0, bcd), normalized
    float b0 = acc[0], b1 = acc[1], b2 = acc[2];
    float pw = rw - rx*b0 - ry*b1 - rz*b2;
    float px = rx + rw*b0 + ry*b2 - rz*b1;
    float py = ry + rw*b1 - rx*b2 + rz*b0;
    float pz = rz + rw*b2 + rx*b1 - ry*b0;
    float pinv = rsqrtf(pw*pw + px*px + py*py + pz*pz);
    pw *= pinv; px *= pinv; py *= pinv; pz *= pinv;
    // t_rel = R(qd)^T * (ts - td)
    float dx = ts4.x - td4.x;
    float dy = ts4.y - td4.y;
    float dz = ts4.z - td4.z;
    float Rd[9];
    quat_to_R(qd.x, qd.y, qd.z, qd.w, Rd);
    float tr0 = Rd[0]*dx + Rd[3]*dy + Rd[6]*dz;
    float tr1 = Rd[1]*dx + Rd[4]*dy + Rd[7]*dz;
    float tr2 = Rd[2]*dx + Rd[5]*dy + Rd[8]*dz;
    // pair_t = t_rel + R(q_rel) @ tvec
    float Rr[9];
    quat_to_R(rw, rx, ry, rz, Rr);
    float t3 = acc[3], t4 = acc[4], t5 = acc[5];
    float pt0 = tr0 + Rr[0]*t3 + Rr[1]*t4 + Rr[2]*t5;
    float pt1 = tr1 + Rr[3]*t3 + Rr[4]*t4 + Rr[5]*t5;
    float pt2 = tr2 + Rr[6]*t3 + Rr[7]*t4 + Rr[8]*t5;

    unsigned ub = dstbits | (pw < 0.f ? 0x80000000u : 0u);
    pay[2*(size_t)pos+0] = make_float4(px, py, pz, __uint_as_float(ub));
    pay[2*(size_t)pos+1] = make_float4(pt0, pt1, pt2, acc[6]);
}

// ---------------- K3: per-node reduction, half-wave per node -----------------
// do_sm!=0 (first iteration): pay[2i+1].w holds logits; compute softmax inline
// and persist weights back. do_sm==0: pay[2i+1].w already holds the weight.
__global__ __launch_bounds__(TPB) void k_node_iter(
    const int* __restrict__ row, float4* __restrict__ pay,
    const float* __restrict__ RT, float* __restrict__ RS, int do_sm, int N)
{
    int g = blockIdx.x * TPB + threadIdx.x;
    int node = g >> 5;
    int ln = threadIdx.x & 31;
    if (node >= N) return;
    int start = row[node], end = row[node + 1];

    float M = 0.f, inv = 0.f;
    if (do_sm) {
        float m = -INFINITY, s = 0.f;
        for (int i = start + ln; i < end; i += 32) {
            float l = pay[2*(size_t)i+1].w;
            float mn = fmaxf(m, l);
            s = s * expf(m - mn) + expf(l - mn);
            m = mn;
        }
        M = hmax32(m);
        float sadj = (m == -INFINITY) ? 0.f : s * expf(m - M);
        float S = hsum32(sadj);
        inv = 1.f / (S + 1e-16f);
    }

    float a00=0,a01=0,a02=0,a10=0,a11=0,a12=0,a20=0,a21=0,a22=0,s0=0,s1=0,s2=0;
    for (int i = start + ln; i < end; i += 32) {
        float4 q  = pay[2*(size_t)i+0];
        float4 tl = pay[2*(size_t)i+1];
        float w;
        if (do_sm) {
            w = expf(tl.w - M) * inv;
            tl.w = w;
            pay[2*(size_t)i+1] = tl;   // persist weight for iters 2,3
        } else {
            w = tl.w;
        }
        unsigned ub = __float_as_uint(q.w);
        int dst = (int)(ub & 0x7fffffffu);
        float s2q = q.x*q.x + q.y*q.y + q.z*q.z;
        float pw = sqrtf(fmaxf(0.f, 1.f - s2q));
        if (ub & 0x80000000u) pw = -pw;
        float P[9];
        quat_to_R(pw, q.x, q.y, q.z, P);
        const float4* rt = (const float4*)(RT + (size_t)dst * 12);
        float4 r0 = rt[0], r1 = rt[1], r2 = rt[2];
        a00 += w * (r0.x*P[0] + r0.y*P[3] + r0.z*P[6]);
        a01 += w * (r0.x*P[1] + r0.y*P[4] + r0.z*P[7]);
        a02 += w * (r0.x*P[2] + r0.y*P[5] + r0.z*P[8]);
        a10 += w * (r1.x*P[0] + r1.y*P[3] + r1.z*P[6]);
        a11 += w * (r1.x*P[1] + r1.y*P[4] + r1.z*P[7]);
        a12 += w * (r1.x*P[2] + r1.y*P[5] + r1.z*P[8]);
        a20 += w * (r2.x*P[0] + r2.y*P[3] + r2.z*P[6]);
        a21 += w * (r2.x*P[1] + r2.y*P[4] + r2.z*P[7]);
        a22 += w * (r2.x*P[2] + r2.y*P[5] + r2.z*P[8]);
        s0 += w * (r0.w + r0.x*tl.x + r0.y*tl.y + r0.z*tl.z);
        s1 += w * (r1.w + r1.x*tl.x + r1.y*tl.y + r1.z*tl.z);
        s2 += w * (r2.w + r2.x*tl.x + r2.y*tl.y + r2.z*tl.z);
    }
    a00 = hsum32(a00); a01 = hsum32(a01); a02 = hsum32(a02);
    a10 = hsum32(a10); a11 = hsum32(a11); a12 = hsum32(a12);
    a20 = hsum32(a20); a21 = hsum32(a21); a22 = hsum32(a22);
    s0 = hsum32(s0); s1 = hsum32(s1); s2 = hsum32(s2);
    if (ln == 0) {
        float4* rs = (float4*)(RS + (size_t)node * 12);
        rs[0] = make_float4(a00, a01, a02, s0);
        rs[1] = make_float4(a10, a11, a12, s1);
        rs[2] = make_float4(a20, a21, a22, s2);
    }
}

// Jacobi rotation zeroing S[p][q]; updates S entries and V columns p,q.
#define JROT(SPP,SQQ,SPQ,SPR,SQR, VP0,VP1,VP2, VQ0,VQ1,VQ2) do { \
    float apq_ = SPQ; \
    if (fabsf(apq_) > 1e-30f) { \
        float tau_ = (SQQ - SPP) / (2.0f * apq_); \
        float tt_ = copysignf(1.0f, tau_) / (fabsf(tau_) + sqrtf(1.0f + tau_*tau_)); \
        float c_ = 1.0f / sqrtf(1.0f + tt_*tt_); \
        float s_ = tt_ * c_; \
        SPP -= tt_ * apq_; SQQ += tt_ * apq_; SPQ = 0.0f; \
        float pr_ = SPR, qr_ = SQR; \
        SPR = c_*pr_ - s_*qr_; SQR = s_*pr_ + c_*qr_; \
        float a_, b_; \
        a_ = VP0; b_ = VQ0; VP0 = c_*a_ - s_*b_; VQ0 = s_*a_ + c_*b_; \
        a_ = VP1; b_ = VQ1; VP1 = c_*a_ - s_*b_; VQ1 = s_*a_ + c_*b_; \
        a_ = VP2; b_ = VQ2; VP2 = c_*a_ - s_*b_; VQ2 = s_*a_ + c_*b_; \
    } \
} while (0)

#define CSW(LA,LB, A0,A1,A2, B0,B1,B2) do { \
    if (LB > LA) { float t_; \
        t_=LA; LA=LB; LB=t_; \
        t_=A0; A0=B0; B0=t_; \
        t_=A1; A1=B1; B1=t_; \
        t_=A2; A2=B2; B2=t_; } \
} while (0)

// ---------------- K5: per-node SVD projection (+ optional finalize) ----------
__global__ __launch_bounds__(TPB) void k_node_project(
    float* __restrict__ RT, const float* __restrict__ RS,
    float* __restrict__ outp, int write_out, int N)
{
    int n = blockIdx.x * TPB + threadIdx.x;
    if (n >= N) return;
    const float4* rs = (const float4*)(RS + (size_t)n * 12);
    float4 q0 = rs[0], q1 = rs[1], q2 = rs[2];
    float A[9] = {q0.x, q0.y, q0.z, q1.x, q1.y, q1.z, q2.x, q2.y, q2.z};
    float t0 = q0.w, t1 = q1.w, t2 = q2.w;

    float s00 = A[0]*A[0] + A[3]*A[3] + A[6]*A[6];
    float s11 = A[1]*A[1] + A[4]*A[4] + A[7]*A[7];
    float s22 = A[2]*A[2] + A[5]*A[5] + A[8]*A[8];
    float s01 = A[0]*A[1] + A[3]*A[4] + A[6]*A[7];
    float s02 = A[0]*A[2] + A[3]*A[5] + A[6]*A[8];
    float s12 = A[1]*A[2] + A[4]*A[5] + A[7]*A[8];
    float v00=1.f,v01=0.f,v02=0.f, v10=0.f,v11=1.f,v12=0.f, v20=0.f,v21=0.f,v22=1.f;
    #pragma unroll
    for (int sweep = 0; sweep < 8; ++sweep) {
        JROT(s00,s11,s01, s02,s12, v00,v10,v20, v01,v11,v21);
        JROT(s00,s22,s02, s01,s12, v00,v10,v20, v02,v12,v22);
        JROT(s11,s22,s12, s01,s02, v01,v11,v21, v02,v12,v22);
    }
    CSW(s00,s11, v00,v10,v20, v01,v11,v21);
    CSW(s00,s22, v00,v10,v20, v02,v12,v22);
    CSW(s11,s22, v01,v11,v21, v02,v12,v22);

    float u0x = A[0]*v00 + A[1]*v10 + A[2]*v20;
    float u0y = A[3]*v00 + A[4]*v10 + A[5]*v20;
    float u0z = A[6]*v00 + A[7]*v10 + A[8]*v20;
    float n0 = sqrtf(u0x*u0x + u0y*u0y + u0z*u0z);
    if (n0 > 1e-20f) { float r = 1.0f/n0; u0x*=r; u0y*=r; u0z*=r; }
    else { u0x = 1.f; u0y = 0.f; u0z = 0.f; }
    float u1x = A[0]*v01 + A[1]*v11 + A[2]*v21;
    float u1y = A[3]*v01 + A[4]*v11 + A[5]*v21;
    float u1z = A[6]*v01 + A[7]*v11 + A[8]*v21;
    float d01 = u1x*u0x + u1y*u0y + u1z*u0z;
    u1x -= d01*u0x; u1y -= d01*u0y; u1z -= d01*u0z;
    float n1 = sqrtf(u1x*u1x + u1y*u1y + u1z*u1z);
    if (n1 > 1e-12f) { float r = 1.0f/n1; u1x*=r; u1y*=r; u1z*=r; }
    else {
        float hx = (fabsf(u0x) < 0.9f) ? 1.f : 0.f;
        float hy = 1.f - hx;
        float cx = -u0z*hy, cy = u0z*hx, cz = u0x*hy - u0y*hx;
        float cn = rsqrtf(cx*cx + cy*cy + cz*cz);
        u1x = cx*cn; u1y = cy*cn; u1z = cz*cn;
    }
    float u2x = u0y*u1z - u0z*u1y;
    float u2y = u0z*u1x - u0x*u1z;
    float u2z = u0x*u1y - u0y*u1x;
    float detV = v00*(v11*v22 - v12*v21) - v01*(v10*v22 - v12*v20) + v02*(v10*v21 - v11*v20);
    if (detV < 0.f) { v02 = -v02; v12 = -v12; v22 = -v22; }
    float m00 = u0x*v00 + u1x*v01 + u2x*v02;
    float m01 = u0x*v10 + u1x*v11 + u2x*v12;
    float m02 = u0x*v20 + u1x*v21 + u2x*v22;
    float m10 = u0y*v00 + u1y*v01 + u2y*v02;
    float m11 = u0y*v10 + u1y*v11 + u2y*v12;
    float m12 = u0y*v20 + u1y*v21 + u2y*v22;
    float m20 = u0z*v00 + u1z*v01 + u2z*v02;
    float m21 = u0z*v10 + u1z*v11 + u2z*v12;
    float m22 = u0z*v20 + u1z*v21 + u2z*v22;
    float4* rt = (float4*)(RT + (size_t)n * 12);
    rt[0] = make_float4(m00, m01, m02, t0);
    rt[1] = make_float4(m10, m11, m12, t1);
    rt[2] = make_float4(m20, m21, m22, t2);

    if (!write_out) return;
    // finalize: rotmat -> quat -> rotvec -> quat (replicates reference)
    float tr = m00 + m11 + m22;
    int idx = 0; float best = tr;
    if (m00 > best) { best = m00; idx = 1; }
    if (m11 > best) { best = m11; idx = 2; }
    if (m22 > best) { best = m22; idx = 3; }
    float qw, qx, qy, qz;
    if (idx == 0)      { qw = 1.f+m00+m11+m22; qx = m21-m12;        qy = m02-m20;        qz = m10-m01; }
    else if (idx == 1) { qw = m21-m12;         qx = 1.f+m00-m11-m22; qy = m01+m10;       qz = m02+m20; }
    else if (idx == 2) { qw = m02-m20;         qx = m01+m10;        qy = 1.f-m00+m11-m22; qz = m12+m21; }
    else               { qw = m10-m01;         qx = m02+m20;        qy = m12+m21;        qz = 1.f-m00-m11+m22; }
    float inv = rsqrtf(qw*qw + qx*qx + qy*qy + qz*qz);
    qw *= inv; qx *= inv; qy *= inv; qz *= inv;
    if (qw < 0.f) { qw = -qw; qx = -qx; qy = -qy; qz = -qz; }
    float vn = sqrtf(qx*qx + qy*qy + qz*qz);
    float theta = 2.f * atan2f(vn, qw);
    float r0v, r1v, r2v;
    if (vn < 1e-6f) { r0v = 2.f*qx; r1v = 2.f*qy; r2v = 2.f*qz; }
    else { float s = theta / vn; r0v = s*qx; r1v = s*qy; r2v = s*qz; }
    float e0 = r0v + 1e-8f, e1 = r1v + 1e-8f, e2 = r2v + 1e-8f;
    float th2 = sqrtf(e0*e0 + e1*e1 + e2*e2);
    float half = 0.5f * th2;
    float cw = cosf(half), sw = sinf(half);
    float it = 1.0f / th2;
    outp[(size_t)n*7+0] = cw;
    outp[(size_t)n*7+1] = sw * r0v * it;
    outp[(size_t)n*7+2] = sw * r1v * it;
    outp[(size_t)n*7+3] = sw * r2v * it;
    outp[(size_t)n*7+4] = t0;
    outp[(size_t)n*7+5] = t1;
    outp[(size_t)n*7+6] = t2;
}

extern "C" void kernel_launch(void* const* d_in, const int* in_sizes, int n_in,
                              void* d_out, int out_size, void* d_ws, size_t ws_size,
                              hipStream_t stream)
{
    (void)n_in; (void)out_size; (void)ws_size;
    const float* ef    = (const float*)d_in[0];
    const float* quats = (const float*)d_in[1];
    const float* trans = (const float*)d_in[2];
    const float* Wu    = (const float*)d_in[3];
    const float* bu    = (const float*)d_in[4];
    const float* Wl    = (const float*)d_in[5];
    const float* bl    = (const float*)d_in[6];
    const int*   ei    = (const int*)d_in[7];
    float* out = (float*)d_out;

    const int N = in_sizes[1] / 4;
    const int E = in_sizes[7] / 2;

    float* ws = (float*)d_ws;
    size_t off = 0;
    float*  qt   = ws + off; off += (size_t)8*N;             // packed quat+trans
    float4* pay  = (float4*)(ws + off); off += (size_t)8*E;  // 2 float4 per edge
    float*  RT   = ws + off; off += (size_t)12*N;
    float*  RS   = ws + off; off += (size_t)12*N;
    int* deg    = (int*)(ws + off); off += (size_t)N;
    int* row    = (int*)(ws + off); off += (size_t)(N + 1);
    int* bsum   = (int*)(ws + off); off += (size_t)SCAN_B;
    int* rank   = (int*)(ws + off); off += (size_t)E;

    int nodeBlocks = (N + TPB - 1) / TPB;
    int edgeBlocks = (E + TPB - 1) / TPB;
    int preBlocks  = (E + TPB_PRE - 1) / TPB_PRE;
    int halfBlocks = (int)(((size_t)N * 32 + TPB - 1) / TPB);
    int scanBlocks = (N + SCAN_B - 1) / SCAN_B;

    k_init<<<nodeBlocks, TPB, 0, stream>>>(quats, trans, qt, RT, deg, N);
    k_hist<<<edgeBlocks, TPB, 0, stream>>>(ei, deg, rank, E);
    k_scan1<<<scanBlocks, SCAN_B, 0, stream>>>(deg, row, bsum, N);
    k_scan2<<<1, SCAN_B, 0, stream>>>(bsum, scanBlocks);
    k_scan3<<<nodeBlocks, TPB, 0, stream>>>(row, bsum, N, E);
    k_edge_pre<<<preBlocks, TPB_PRE, 0, stream>>>(ef, ei, qt, Wu, bu, Wl, bl,
                                                  row, rank, pay, E);
    k_node_iter<<<halfBlocks, TPB, 0, stream>>>(row, pay, RT, RS, 1, N);
    k_node_project<<<nodeBlocks, TPB, 0, stream>>>(RT, RS, out, 0, N);
    k_node_iter<<<halfBlocks, TPB, 0, stream>>>(row, pay, RT, RS, 0, N);
    k_node_project<<<nodeBlocks, TPB, 0, stream>>>(RT, RS, out, 0, N);
    k_node_iter<<<halfBlocks, TPB, 0, stream>>>(row, pay, RT, RS, 0, N);
    k_node_project<<<nodeBlocks, TPB, 0, stream>>>(RT, RS, out, 1, N);
}

// Round 14
// 343.028 us; speedup vs baseline: 1.0417x; 1.0417x over previous
//
#include <hip/hip_runtime.h>
#include <math.h>

#define TPB 256
#define SCAN_B 1024

__device__ __forceinline__ void quat_to_R(float w, float x, float y, float z, float* R) {
    R[0] = 1.f - 2.f*(y*y + z*z);
    R[1] = 2.f*(x*y - w*z);
    R[2] = 2.f*(x*z + w*y);
    R[3] = 2.f*(x*y + w*z);
    R[4] = 1.f - 2.f*(x*x + z*z);
    R[5] = 2.f*(y*z - w*x);
    R[6] = 2.f*(x*z - w*y);
    R[7] = 2.f*(y*z + w*x);
    R[8] = 1.f - 2.f*(x*x + y*y);
}

// 32-lane (half-wave) reductions: xor offsets < 32 stay within each half.
__device__ __forceinline__ float hsum32(float v) {
    #pragma unroll
    for (int o = 16; o > 0; o >>= 1) v += __shfl_xor(v, o);
    return v;
}
__device__ __forceinline__ float hmax32(float v) {
    #pragma unroll
    for (int o = 16; o > 0; o >>= 1) v = fmaxf(v, __shfl_xor(v, o));
    return v;
}

// ---------------- K0: per-node init ----------------
// qt layout per node (32 B): [w,x,y,z][t0,t1,t2,0]
// RT layout per node: [r00,r01,r02,t0][r10,r11,r12,t1][r20,r21,r22,t2]
__global__ __launch_bounds__(TPB) void k_init(
    const float* __restrict__ quats, const float* __restrict__ trans,
    float* __restrict__ qt, float* __restrict__ RT, int* __restrict__ deg, int N)
{
    int n = blockIdx.x * TPB + threadIdx.x;
    if (n >= N) return;
    float4 q = ((const float4*)quats)[n];
    float inv = rsqrtf(q.x*q.x + q.y*q.y + q.z*q.z + q.w*q.w);
    float w = q.x*inv, x = q.y*inv, y = q.z*inv, z = q.w*inv;
    float t0 = trans[(size_t)n*3+0], t1 = trans[(size_t)n*3+1], t2 = trans[(size_t)n*3+2];
    float4* qtp = (float4*)(qt + (size_t)n*8);
    qtp[0] = make_float4(w, x, y, z);
    qtp[1] = make_float4(t0, t1, t2, 0.f);
    float R[9];
    quat_to_R(w, x, y, z, R);
    float4* rt = (float4*)(RT + (size_t)n*12);
    rt[0] = make_float4(R[0], R[1], R[2], t0);
    rt[1] = make_float4(R[3], R[4], R[5], t1);
    rt[2] = make_float4(R[6], R[7], R[8], t2);
    deg[n] = 0;
}

// ---------------- K1: histogram of src ----------------
__global__ __launch_bounds__(TPB) void k_hist(
    const int* __restrict__ ei, int* __restrict__ deg, int E)
{
    int e = blockIdx.x * TPB + threadIdx.x;
    if (e >= E) return;
    atomicAdd(deg + ei[(size_t)E + e], 1);
}

// ---------------- scan: deg -> row (exclusive) ----------------
__global__ __launch_bounds__(SCAN_B) void k_scan1(
    const int* __restrict__ deg, int* __restrict__ row, int* __restrict__ bsum, int N)
{
    __shared__ int sh[SCAN_B];
    int i = blockIdx.x * SCAN_B + threadIdx.x;
    int v = (i < N) ? deg[i] : 0;
    sh[threadIdx.x] = v;
    __syncthreads();
    #pragma unroll
    for (int o = 1; o < SCAN_B; o <<= 1) {
        int t = (threadIdx.x >= o) ? sh[threadIdx.x - o] : 0;
        __syncthreads();
        sh[threadIdx.x] += t;
        __syncthreads();
    }
    if (i < N) row[i] = sh[threadIdx.x] - v;
    if (threadIdx.x == SCAN_B - 1) bsum[blockIdx.x] = sh[SCAN_B - 1];
}

__global__ __launch_bounds__(SCAN_B) void k_scan2(int* __restrict__ bsum, int nb)
{
    __shared__ int sh[SCAN_B];
    int v = (threadIdx.x < nb) ? bsum[threadIdx.x] : 0;
    sh[threadIdx.x] = v;
    __syncthreads();
    #pragma unroll
    for (int o = 1; o < SCAN_B; o <<= 1) {
        int t = (threadIdx.x >= o) ? sh[threadIdx.x - o] : 0;
        __syncthreads();
        sh[threadIdx.x] += t;
        __syncthreads();
    }
    if (threadIdx.x < nb) bsum[threadIdx.x] = sh[threadIdx.x] - v;
}

__global__ __launch_bounds__(TPB) void k_scan3(
    int* __restrict__ row, const int* __restrict__ bsum,
    int* __restrict__ cursor, int N, int E)
{
    int i = blockIdx.x * TPB + threadIdx.x;
    if (i >= N) return;
    int v = row[i] + bsum[i >> 10];
    row[i] = v;
    cursor[i] = v;
    if (i == 0) row[N] = E;
}

// ---------------- K2: per-edge precompute, LDS-staged two-phase (R11) --------
__global__ __launch_bounds__(TPB) void k_edge_pre(
    const float* __restrict__ ef, const int* __restrict__ ei,
    const float* __restrict__ qt,
    const float* __restrict__ Wu, const float* __restrict__ bu,
    const float* __restrict__ Wl, const float* __restrict__ bl,
    int* __restrict__ cursor, float4* __restrict__ pay, int E)
{
    __shared__ __align__(16) float Ws[7][64];
    __shared__ float accS[256][7];
    for (int i = threadIdx.x; i < 7*64; i += TPB) {
        int j = i >> 6, k = i & 63;
        Ws[j][k] = (j < 6) ? Wu[k*6 + j] : Wl[k];
    }
    __syncthreads();

    int tid = threadIdx.x;
    int sub = tid & 3, eL = tid >> 2;
    int blockStart = blockIdx.x * TPB;

    // ---- hoisted tail gathers (latency hides under the stream phase) ----
    int eT = blockStart + tid;
    int dst = 0, src = 0;
    float4 qd = make_float4(1.f,0.f,0.f,0.f), qs = qd;
    float4 td4 = make_float4(0.f,0.f,0.f,0.f), ts4 = td4;
    if (eT < E) {
        dst = ei[eT];
        src = ei[(size_t)E + eT];
        const float4* pd = (const float4*)(qt + (size_t)dst*8);
        const float4* ps = (const float4*)(qt + (size_t)src*8);
        qd  = pd[0]; td4 = pd[1];
        qs  = ps[0]; ts4 = ps[1];
    }

    // ---- phase 1: stream ef ----
    #pragma unroll
    for (int r = 0; r < 4; ++r) {
        int el = r * 64 + eL;
        int e = blockStart + el;
        float acc[7] = {0.f,0.f,0.f,0.f,0.f,0.f,0.f};
        if (e < E) {
            const float4* ef4 = (const float4*)(ef + (size_t)e * 64) + sub * 4;
            #pragma unroll
            for (int k = 0; k < 4; ++k) {
                float4 v = ef4[k];
                #pragma unroll
                for (int j = 0; j < 7; ++j) {
                    float4 w = ((const float4*)Ws[j])[sub*4 + k];
                    acc[j] = fmaf(v.x, w.x, fmaf(v.y, w.y, fmaf(v.z, w.z, fmaf(v.w, w.w, acc[j]))));
                }
            }
        }
        #pragma unroll
        for (int j = 0; j < 7; ++j) {
            acc[j] += __shfl_xor(acc[j], 1);
            acc[j] += __shfl_xor(acc[j], 2);
        }
        if (sub == 0) {
            #pragma unroll
            for (int j = 0; j < 7; ++j) accS[el][j] = acc[j];
        }
    }
    __syncthreads();

    // ---- phase 2: tail, 1 thread = 1 edge ----
    if (eT >= E) return;
    float acc[7];
    #pragma unroll
    for (int j = 0; j < 7; ++j) acc[j] = accS[tid][j];
    #pragma unroll
    for (int j = 0; j < 6; ++j) acc[j] += bu[j];
    acc[6] += bl[0];

    // q_rel = conj(qd) * qs
    float aw = qd.x, ax = -qd.y, ay = -qd.z, az = -qd.w;
    float bw = qs.x, bx = qs.y, by = qs.z, bz = qs.w;
    float rw = aw*bw - ax*bx - ay*by - az*bz;
    float rx = aw*bx + ax*bw + ay*bz - az*by;
    float ry = aw*by - ax*bz + ay*bw + az*bx;
    float rz = aw*bz + ax*by - ay*bx + az*bw;
    // pair_q = q_rel + q_rel * (0, bcd), normalized
    float b0 = acc[0], b1 = acc[1], b2 = acc[2];
    float pw = rw - rx*b0 - ry*b1 - rz*b2;
    float px = rx + rw*b0 + ry*b2 - rz*b1;
    float py = ry + rw*b1 - rx*b2 + rz*b0;
    float pz = rz + rw*b2 + rx*b1 - ry*b0;
    float pinv = rsqrtf(pw*pw + px*px + py*py + pz*pz);
    pw *= pinv; px *= pinv; py *= pinv; pz *= pinv;
    // t_rel = R(qd)^T * (ts - td)
    float dx = ts4.x - td4.x;
    float dy = ts4.y - td4.y;
    float dz = ts4.z - td4.z;
    float Rd[9];
    quat_to_R(qd.x, qd.y, qd.z, qd.w, Rd);
    float tr0 = Rd[0]*dx + Rd[3]*dy + Rd[6]*dz;
    float tr1 = Rd[1]*dx + Rd[4]*dy + Rd[7]*dz;
    float tr2 = Rd[2]*dx + Rd[5]*dy + Rd[8]*dz;
    // pair_t = t_rel + R(q_rel) @ tvec
    float Rr[9];
    quat_to_R(rw, rx, ry, rz, Rr);
    float t3 = acc[3], t4 = acc[4], t5 = acc[5];
    float pt0 = tr0 + Rr[0]*t3 + Rr[1]*t4 + Rr[2]*t5;
    float pt1 = tr1 + Rr[3]*t3 + Rr[4]*t4 + Rr[5]*t5;
    float pt2 = tr2 + Rr[6]*t3 + Rr[7]*t4 + Rr[8]*t5;

    int pos = atomicAdd(cursor + src, 1);
    unsigned ub = (unsigned)dst | (pw < 0.f ? 0x80000000u : 0u);
    pay[2*(size_t)pos+0] = make_float4(px, py, pz, __uint_as_float(ub));
    pay[2*(size_t)pos+1] = make_float4(pt0, pt1, pt2, acc[6]);
}

// ---------------- K3: per-node reduction, half-wave per node -----------------
// do_sm!=0 (first iteration): pay[2i+1].w holds logits; compute softmax inline
// (max/sum pass over L3-resident pay, then accumulate with w=exp(l-M)*inv and
// persist w back). do_sm==0: pay[2i+1].w already holds the weight.
__global__ __launch_bounds__(TPB) void k_node_iter(
    const int* __restrict__ row, float4* __restrict__ pay,
    const float* __restrict__ RT, float* __restrict__ RS, int do_sm, int N)
{
    int g = blockIdx.x * TPB + threadIdx.x;
    int node = g >> 5;
    int ln = threadIdx.x & 31;
    if (node >= N) return;
    int start = row[node], end = row[node + 1];

    float M = 0.f, inv = 0.f;
    if (do_sm) {
        float m = -INFINITY, s = 0.f;
        for (int i = start + ln; i < end; i += 32) {
            float l = pay[2*(size_t)i+1].w;
            float mn = fmaxf(m, l);
            s = s * expf(m - mn) + expf(l - mn);
            m = mn;
        }
        M = hmax32(m);
        float sadj = (m == -INFINITY) ? 0.f : s * expf(m - M);
        float S = hsum32(sadj);
        inv = 1.f / (S + 1e-16f);
    }

    float a00=0,a01=0,a02=0,a10=0,a11=0,a12=0,a20=0,a21=0,a22=0,s0=0,s1=0,s2=0;
    for (int i = start + ln; i < end; i += 32) {
        float4 q  = pay[2*(size_t)i+0];
        float4 tl = pay[2*(size_t)i+1];
        float w;
        if (do_sm) {
            w = expf(tl.w - M) * inv;
            tl.w = w;
            pay[2*(size_t)i+1] = tl;   // persist weight for iters 2,3
        } else {
            w = tl.w;
        }
        unsigned ub = __float_as_uint(q.w);
        int dst = (int)(ub & 0x7fffffffu);
        float s2q = q.x*q.x + q.y*q.y + q.z*q.z;
        float pw = sqrtf(fmaxf(0.f, 1.f - s2q));
        if (ub & 0x80000000u) pw = -pw;
        float P[9];
        quat_to_R(pw, q.x, q.y, q.z, P);
        const float4* rt = (const float4*)(RT + (size_t)dst * 12);
        float4 r0 = rt[0], r1 = rt[1], r2 = rt[2];
        a00 += w * (r0.x*P[0] + r0.y*P[3] + r0.z*P[6]);
        a01 += w * (r0.x*P[1] + r0.y*P[4] + r0.z*P[7]);
        a02 += w * (r0.x*P[2] + r0.y*P[5] + r0.z*P[8]);
        a10 += w * (r1.x*P[0] + r1.y*P[3] + r1.z*P[6]);
        a11 += w * (r1.x*P[1] + r1.y*P[4] + r1.z*P[7]);
        a12 += w * (r1.x*P[2] + r1.y*P[5] + r1.z*P[8]);
        a20 += w * (r2.x*P[0] + r2.y*P[3] + r2.z*P[6]);
        a21 += w * (r2.x*P[1] + r2.y*P[4] + r2.z*P[7]);
        a22 += w * (r2.x*P[2] + r2.y*P[5] + r2.z*P[8]);
        s0 += w * (r0.w + r0.x*tl.x + r0.y*tl.y + r0.z*tl.z);
        s1 += w * (r1.w + r1.x*tl.x + r1.y*tl.y + r1.z*tl.z);
        s2 += w * (r2.w + r2.x*tl.x + r2.y*tl.y + r2.z*tl.z);
    }
    a00 = hsum32(a00); a01 = hsum32(a01); a02 = hsum32(a02);
    a10 = hsum32(a10); a11 = hsum32(a11); a12 = hsum32(a12);
    a20 = hsum32(a20); a21 = hsum32(a21); a22 = hsum32(a22);
    s0 = hsum32(s0); s1 = hsum32(s1); s2 = hsum32(s2);
    if (ln == 0) {
        float4* rs = (float4*)(RS + (size_t)node * 12);
        rs[0] = make_float4(a00, a01, a02, s0);
        rs[1] = make_float4(a10, a11, a12, s1);
        rs[2] = make_float4(a20, a21, a22, s2);
    }
}

// Jacobi rotation zeroing S[p][q]; updates S entries and V columns p,q.
#define JROT(SPP,SQQ,SPQ,SPR,SQR, VP0,VP1,VP2, VQ0,VQ1,VQ2) do { \
    float apq_ = SPQ; \
    if (fabsf(apq_) > 1e-30f) { \
        float tau_ = (SQQ - SPP) / (2.0f * apq_); \
        float tt_ = copysignf(1.0f, tau_) / (fabsf(tau_) + sqrtf(1.0f + tau_*tau_)); \
        float c_ = 1.0f / sqrtf(1.0f + tt_*tt_); \
        float s_ = tt_ * c_; \
        SPP -= tt_ * apq_; SQQ += tt_ * apq_; SPQ = 0.0f; \
        float pr_ = SPR, qr_ = SQR; \
        SPR = c_*pr_ - s_*qr_; SQR = s_*pr_ + c_*qr_; \
        float a_, b_; \
        a_ = VP0; b_ = VQ0; VP0 = c_*a_ - s_*b_; VQ0 = s_*a_ + c_*b_; \
        a_ = VP1; b_ = VQ1; VP1 = c_*a_ - s_*b_; VQ1 = s_*a_ + c_*b_; \
        a_ = VP2; b_ = VQ2; VP2 = c_*a_ - s_*b_; VQ2 = s_*a_ + c_*b_; \
    } \
} while (0)

#define CSW(LA,LB, A0,A1,A2, B0,B1,B2) do { \
    if (LB > LA) { float t_; \
        t_=LA; LA=LB; LB=t_; \
        t_=A0; A0=B0; B0=t_; \
        t_=A1; A1=B1; B1=t_; \
        t_=A2; A2=B2; B2=t_; } \
} while (0)

// ---------------- K5: per-node SVD projection (+ optional finalize) ----------
__global__ __launch_bounds__(TPB) void k_node_project(
    float* __restrict__ RT, const float* __restrict__ RS,
    float* __restrict__ outp, int write_out, int N)
{
    int n = blockIdx.x * TPB + threadIdx.x;
    if (n >= N) return;
    const float4* rs = (const float4*)(RS + (size_t)n * 12);
    float4 q0 = rs[0], q1 = rs[1], q2 = rs[2];
    float A[9] = {q0.x, q0.y, q0.z, q1.x, q1.y, q1.z, q2.x, q2.y, q2.z};
    float t0 = q0.w, t1 = q1.w, t2 = q2.w;

    float s00 = A[0]*A[0] + A[3]*A[3] + A[6]*A[6];
    float s11 = A[1]*A[1] + A[4]*A[4] + A[7]*A[7];
    float s22 = A[2]*A[2] + A[5]*A[5] + A[8]*A[8];
    float s01 = A[0]*A[1] + A[3]*A[4] + A[6]*A[7];
    float s02 = A[0]*A[2] + A[3]*A[5] + A[6]*A[8];
    float s12 = A[1]*A[2] + A[4]*A[5] + A[7]*A[8];
    float v00=1.f,v01=0.f,v02=0.f, v10=0.f,v11=1.f,v12=0.f, v20=0.f,v21=0.f,v22=1.f;
    #pragma unroll
    for (int sweep = 0; sweep < 8; ++sweep) {
        JROT(s00,s11,s01, s02,s12, v00,v10,v20, v01,v11,v21);
        JROT(s00,s22,s02, s01,s12, v00,v10,v20, v02,v12,v22);
        JROT(s11,s22,s12, s01,s02, v01,v11,v21, v02,v12,v22);
    }
    CSW(s00,s11, v00,v10,v20, v01,v11,v21);
    CSW(s00,s22, v00,v10,v20, v02,v12,v22);
    CSW(s11,s22, v01,v11,v21, v02,v12,v22);

    float u0x = A[0]*v00 + A[1]*v10 + A[2]*v20;
    float u0y = A[3]*v00 + A[4]*v10 + A[5]*v20;
    float u0z = A[6]*v00 + A[7]*v10 + A[8]*v20;
    float n0 = sqrtf(u0x*u0x + u0y*u0y + u0z*u0z);
    if (n0 > 1e-20f) { float r = 1.0f/n0; u0x*=r; u0y*=r; u0z*=r; }
    else { u0x = 1.f; u0y = 0.f; u0z = 0.f; }
    float u1x = A[0]*v01 + A[1]*v11 + A[2]*v21;
    float u1y = A[3]*v01 + A[4]*v11 + A[5]*v21;
    float u1z = A[6]*v01 + A[7]*v11 + A[8]*v21;
    float d01 = u1x*u0x + u1y*u0y + u1z*u0z;
    u1x -= d01*u0x; u1y -= d01*u0y; u1z -= d01*u0z;
    float n1 = sqrtf(u1x*u1x + u1y*u1y + u1z*u1z);
    if (n1 > 1e-12f) { float r = 1.0f/n1; u1x*=r; u1y*=r; u1z*=r; }
    else {
        float hx = (fabsf(u0x) < 0.9f) ? 1.f : 0.f;
        float hy = 1.f - hx;
        float cx = -u0z*hy, cy = u0z*hx, cz = u0x*hy - u0y*hx;
        float cn = rsqrtf(cx*cx + cy*cy + cz*cz);
        u1x = cx*cn; u1y = cy*cn; u1z = cz*cn;
    }
    float u2x = u0y*u1z - u0z*u1y;
    float u2y = u0z*u1x - u0x*u1z;
    float u2z = u0x*u1y - u0y*u1x;
    float detV = v00*(v11*v22 - v12*v21) - v01*(v10*v22 - v12*v20) + v02*(v10*v21 - v11*v20);
    if (detV < 0.f) { v02 = -v02; v12 = -v12; v22 = -v22; }
    float m00 = u0x*v00 + u1x*v01 + u2x*v02;
    float m01 = u0x*v10 + u1x*v11 + u2x*v12;
    float m02 = u0x*v20 + u1x*v21 + u2x*v22;
    float m10 = u0y*v00 + u1y*v01 + u2y*v02;
    float m11 = u0y*v10 + u1y*v11 + u2y*v12;
    float m12 = u0y*v20 + u1y*v21 + u2y*v22;
    float m20 = u0z*v00 + u1z*v01 + u2z*v02;
    float m21 = u0z*v10 + u1z*v11 + u2z*v12;
    float m22 = u0z*v20 + u1z*v21 + u2z*v22;
    float4* rt = (float4*)(RT + (size_t)n * 12);
    rt[0] = make_float4(m00, m01, m02, t0);
    rt[1] = make_float4(m10, m11, m12, t1);
    rt[2] = make_float4(m20, m21, m22, t2);

    if (!write_out) return;
    // finalize: rotmat -> quat -> rotvec -> quat (replicates reference)
    float tr = m00 + m11 + m22;
    int idx = 0; float best = tr;
    if (m00 > best) { best = m00; idx = 1; }
    if (m11 > best) { best = m11; idx = 2; }
    if (m22 > best) { best = m22; idx = 3; }
    float qw, qx, qy, qz;
    if (idx == 0)      { qw = 1.f+m00+m11+m22; qx = m21-m12;        qy = m02-m20;        qz = m10-m01; }
    else if (idx == 1) { qw = m21-m12;         qx = 1.f+m00-m11-m22; qy = m01+m10;       qz = m02+m20; }
    else if (idx == 2) { qw = m02-m20;         qx = m01+m10;        qy = 1.f-m00+m11-m22; qz = m12+m21; }
    else               { qw = m10-m01;         qx = m02+m20;        qy = m12+m21;        qz = 1.f-m00-m11+m22; }
    float inv = rsqrtf(qw*qw + qx*qx + qy*qy + qz*qz);
    qw *= inv; qx *= inv; qy *= inv; qz *= inv;
    if (qw < 0.f) { qw = -qw; qx = -qx; qy = -qy; qz = -qz; }
    float vn = sqrtf(qx*qx + qy*qy + qz*qz);
    float theta = 2.f * atan2f(vn, qw);
    float r0v, r1v, r2v;
    if (vn < 1e-6f) { r0v = 2.f*qx; r1v = 2.f*qy; r2v = 2.f*qz; }
    else { float s = theta / vn; r0v = s*qx; r1v = s*qy; r2v = s*qz; }
    float e0 = r0v + 1e-8f, e1 = r1v + 1e-8f, e2 = r2v + 1e-8f;
    float th2 = sqrtf(e0*e0 + e1*e1 + e2*e2);
    float half = 0.5f * th2;
    float cw = cosf(half), sw = sinf(half);
    float it = 1.0f / th2;
    outp[(size_t)n*7+0] = cw;
    outp[(size_t)n*7+1] = sw * r0v * it;
    outp[(size_t)n*7+2] = sw * r1v * it;
    outp[(size_t)n*7+3] = sw * r2v * it;
    outp[(size_t)n*7+4] = t0;
    outp[(size_t)n*7+5] = t1;
    outp[(size_t)n*7+6] = t2;
}

extern "C" void kernel_launch(void* const* d_in, const int* in_sizes, int n_in,
                              void* d_out, int out_size, void* d_ws, size_t ws_size,
                              hipStream_t stream)
{
    (void)n_in; (void)out_size; (void)ws_size;
    const float* ef    = (const float*)d_in[0];
    const float* quats = (const float*)d_in[1];
    const float* trans = (const float*)d_in[2];
    const float* Wu    = (const float*)d_in[3];
    const float* bu    = (const float*)d_in[4];
    const float* Wl    = (const float*)d_in[5];
    const float* bl    = (const float*)d_in[6];
    const int*   ei    = (const int*)d_in[7];
    float* out = (float*)d_out;

    const int N = in_sizes[1] / 4;
    const int E = in_sizes[7] / 2;

    float* ws = (float*)d_ws;
    size_t off = 0;
    float*  qt   = ws + off; off += (size_t)8*N;             // packed quat+trans
    float4* pay  = (float4*)(ws + off); off += (size_t)8*E;  // 2 float4 per edge
    float*  RT   = ws + off; off += (size_t)12*N;
    float*  RS   = ws + off; off += (size_t)12*N;
    int* deg    = (int*)(ws + off); off += (size_t)N;        // reused as cursor
    int* row    = (int*)(ws + off); off += (size_t)(N + 1);
    int* bsum   = (int*)(ws + off); off += (size_t)SCAN_B;

    int nodeBlocks = (N + TPB - 1) / TPB;
    int edgeBlocks = (E + TPB - 1) / TPB;
    int halfBlocks = (int)(((size_t)N * 32 + TPB - 1) / TPB);
    int scanBlocks = (N + SCAN_B - 1) / SCAN_B;

    k_init<<<nodeBlocks, TPB, 0, stream>>>(quats, trans, qt, RT, deg, N);
    k_hist<<<edgeBlocks, TPB, 0, stream>>>(ei, deg, E);
    k_scan1<<<scanBlocks, SCAN_B, 0, stream>>>(deg, row, bsum, N);
    k_scan2<<<1, SCAN_B, 0, stream>>>(bsum, scanBlocks);
    k_scan3<<<nodeBlocks, TPB, 0, stream>>>(row, bsum, deg, N, E);
    k_edge_pre<<<edgeBlocks, TPB, 0, stream>>>(ef, ei, qt, Wu, bu, Wl, bl,
                                               deg, pay, E);
    k_node_iter<<<halfBlocks, TPB, 0, stream>>>(row, pay, RT, RS, 1, N);
    k_node_project<<<nodeBlocks, TPB, 0, stream>>>(RT, RS, out, 0, N);
    k_node_iter<<<halfBlocks, TPB, 0, stream>>>(row, pay, RT, RS, 0, N);
    k_node_project<<<nodeBlocks, TPB, 0, stream>>>(RT, RS, out, 0, N);
    k_node_iter<<<halfBlocks, TPB, 0, stream>>>(row, pay, RT, RS, 0, N);
    k_node_project<<<nodeBlocks, TPB, 0, stream>>>(RT, RS, out, 1, N);
}